// Round 11
// baseline (108.801 us; speedup 1.0000x reference)
//
#include <hip/hip_runtime.h>
#include <math.h>

#define B_ 64
#define L_ 512
#define N_ 321
#define P_ 720
#define E_ 8
#define R_ 32
#define CID_ 32
#define H_ 64
#define ER_ 256
#define KB2 288      // ER_ + 8 bias-rank + 1 mean + 23 zero-pad
#define HGROWS 384   // 6 n-tiles x 64 (rows >= N_ hold junk, never used)

typedef __attribute__((ext_vector_type(8))) short bf16x8;
typedef __attribute__((ext_vector_type(4))) float f32x4;
typedef __attribute__((ext_vector_type(8))) unsigned short u16x8;
typedef __attribute__((ext_vector_type(4))) unsigned short u16x4;

// workspace layout (float offsets)
#define OFF_GATE 0                        // 2568
#define OFF_CS1  2568                     // 256
#define OFF_MEAN 2824                     // 64*384 = 24576
#define OFF_SDEV 27400                    // 24576
#define OFF_P1   51976                    // 64*384*8 = 196608
#define OFF_P2   248584                   // 196608
#define OFF_W1K  445192                   // bf16 256*512 = 65536 f
#define OFF_W2X  510728                   // bf16 720*288 = 103680 f
#define OFF_XT   614408                   // bf16 64*384*512 = 6291456 f
#define OFF_HG   6905864                  // bf16 64*384*288 = 3538944 f
// total ~41.8 MB

__device__ __forceinline__ unsigned short f2bf(float f) {
    unsigned u = __float_as_uint(f);
    u += 0x7fffu + ((u >> 16) & 1u);
    return (unsigned short)(u >> 16);
}
__device__ __forceinline__ float bf2f(unsigned short h) {
    return __uint_as_float(((unsigned)h) << 16);
}

// ---------------- router ----------------------------------------------------
__global__ void router_kernel(const float* __restrict__ ident,
                              const float* __restrict__ rw1, const float* __restrict__ rb1,
                              const float* __restrict__ rw2, const float* __restrict__ rb2,
                              float* __restrict__ gate) {
    int n = blockIdx.x;
    int t = threadIdx.x;  // 0..63
    __shared__ float hid[H_];
    __shared__ float lg[E_];
    float acc = rb1[t];
    #pragma unroll
    for (int c = 0; c < CID_; ++c)
        acc = fmaf(ident[n*CID_ + c], rw1[c*H_ + t], acc);
    hid[t] = fmaxf(acc, 0.f);
    __syncthreads();
    if (t < E_) {
        float a = rb2[t];
        #pragma unroll
        for (int h = 0; h < H_; ++h) a = fmaf(hid[h], rw2[h*E_ + t], a);
        lg[t] = a;
    }
    __syncthreads();
    if (t == 0) {
        float m = lg[0];
        #pragma unroll
        for (int e = 1; e < E_; ++e) m = fmaxf(m, lg[e]);
        float s = 0.f, ex[E_];
        #pragma unroll
        for (int e = 0; e < E_; ++e) { ex[e] = expf(lg[e] - m); s += ex[e]; }
        float inv = 1.f / s;
        #pragma unroll
        for (int e = 0; e < E_; ++e) gate[n*E_ + e] = ex[e] * inv;
    }
}

// ---------------- prep: w1k [er][l], w2x [p][288], cs1 ----------------------
__global__ void prep_kernel(const float* __restrict__ w1, const float* __restrict__ w2,
                            const float* __restrict__ bias,
                            unsigned short* __restrict__ w1k, unsigned short* __restrict__ w2x,
                            float* __restrict__ cs1) {
    __shared__ float red[16][32];
    int bid = blockIdx.x, t = threadIdx.x;
    if (bid < 256) {                  // w1k [er][l]: 256*512 elems
        int g = bid*512 + t;
        int er = g >> 9, l = g & 511;
        w1k[g] = f2bf(w1[(size_t)(er >> 5)*(L_*R_) + (size_t)l*R_ + (er & 31)]);
    } else if (bid < 256 + 720) {     // w2x row p: K-extended
        int p = bid - 256;
        if (t < KB2) {
            unsigned short v;
            if (t < ER_)            v = f2bf(w2[(size_t)t*P_ + p]);
            else if (t < ER_ + E_)  v = f2bf(bias[(size_t)(t - ER_)*P_ + p]);
            else if (t == ER_ + E_) v = 0x3f80;  // bf16(1.0) for the mean lane
            else                    v = 0;
            w2x[(size_t)p*KB2 + t] = v;
        }
    } else {                          // cs1: 8 blocks, one expert each
        int e = bid - 976;
        int q = t >> 5, r = t & 31;
        float s = 0.f;
        for (int l = q; l < L_; l += 16)
            s += bf2f(f2bf(w1[(size_t)e*(L_*R_) + (size_t)l*R_ + r]));
        red[q][r] = s;
        __syncthreads();
        if (q == 0) {
            #pragma unroll
            for (int qq = 1; qq < 16; ++qq) s += red[qq][r];
            cs1[e*32 + r] = s;
        }
    }
}

// ---------------- prepx: x[b,l,n] -> xT[b,n,l] bf16 + stats partials --------
// grid 3072 = 64b * 8kc * 6nt, 256 thr, NO LDS (8 blocks/CU). Thread owns one
// n-column x 16 k: register column IS the transpose; 32B contiguous stores.
__global__ __launch_bounds__(256) void prepx_kernel(
        const float* __restrict__ x, unsigned short* __restrict__ xT,
        float* __restrict__ p1, float* __restrict__ p2) {
    const int bid = blockIdx.x;
    const int b   = bid / 48;
    const int rem = bid % 48;
    const int kc  = rem >> 3;            // wait: 48 = 8kc*6nt -> kc = rem/6
    const int kcc = rem / 6;             // 0..7
    const int nt  = rem % 6;             // 0..5
    const int n0  = nt * 64;
    (void)kc;

    const int t  = threadIdx.x;
    const int nn = t >> 2;               // 0..63
    const int q  = t & 3;                // 0..3 (16 k each)

    const int gn = n0 + nn;
    const int gnc = (gn < N_) ? gn : (N_ - 1);   // clamped (junk cols ok)
    const float* xp = x + (size_t)b * L_ * N_ + gnc;
    const int k0 = kcc*64 + q*16;

    float v[16];
    #pragma unroll
    for (int i = 0; i < 16; ++i)
        v[i] = xp[(size_t)(k0 + i) * N_];

    float s1 = 0.f, s2 = 0.f;
    u16x8 pk0, pk1;
    #pragma unroll
    for (int i = 0; i < 8; ++i) {
        s1 += v[i]; s2 = fmaf(v[i], v[i], s2); pk0[i] = f2bf(v[i]);
    }
    #pragma unroll
    for (int i = 0; i < 8; ++i) {
        float f = v[8+i];
        s1 += f; s2 = fmaf(f, f, s2); pk1[i] = f2bf(f);
    }
    unsigned short* xrow = xT + ((size_t)b*HGROWS + gn) * L_ + k0;   // gn<384 always
    *(u16x8*)&xrow[0] = pk0;
    *(u16x8*)&xrow[8] = pk1;

    // reduce over q (lane bits 0..1) -> chunk partials
    s1 += __shfl_xor(s1, 1); s1 += __shfl_xor(s1, 2);
    s2 += __shfl_xor(s2, 1); s2 += __shfl_xor(s2, 2);
    if (q == 0) {
        size_t pidx = ((size_t)b*HGROWS + gn) * 8 + kcc;
        p1[pidx] = s1;
        p2[pidx] = s2;
    }
}

// ---------------- statred: partials -> mean/sd -------------------------------
__global__ __launch_bounds__(256) void statred_kernel(
        const float* __restrict__ p1, const float* __restrict__ p2,
        float* __restrict__ meanv, float* __restrict__ sdev) {
    int id = blockIdx.x*256 + threadIdx.x;   // 0..64*384-1
    float a = 0.f, qq = 0.f;
    #pragma unroll
    for (int kc = 0; kc < 8; ++kc) { a += p1[(size_t)id*8 + kc]; qq += p2[(size_t)id*8 + kc]; }
    float mean = a * (1.f/L_);
    float var = (qq - (float)L_*mean*mean) * (1.f/(L_-1));
    var = fmaxf(var, 0.f);
    meanv[id] = mean;
    sdev[id]  = sqrtf(var) + 1e-6f;
}

// ---------------- GEMM1: barrier-free, LDS-free ------------------------------
// grid 384 = 8 xcd * (8 b * 6 nt), 512 thr. Wave owns 32er x 64n x K=512.
// A-frags: L2-hot w1k reg ring. B-frags: direct from xT (L2-resident tile).
__global__ __launch_bounds__(512, 4) void gemm1_kernel(
        const unsigned short* __restrict__ xT, const unsigned short* __restrict__ w1k,
        const float* __restrict__ gate, const float* __restrict__ cs1,
        const float* __restrict__ meanv, const float* __restrict__ sdev,
        unsigned short* __restrict__ hg) {
    const int bid = blockIdx.x;
    const int xcd = bid & 7;
    const int idx = bid >> 3;            // 0..47
    const int b   = (xcd << 3) + idx / 6;
    const int n0  = (idx % 6) * 64;

    const int tid  = threadIdx.x;
    const int lane = tid & 63;
    const int wave = tid >> 6;          // 0..7
    const int l15  = lane & 15;
    const int kgrp = lane >> 4;         // 0..3

    const unsigned short* apA = w1k + (size_t)(wave*32 + l15)*L_;
    const unsigned short* apB = w1k + (size_t)(wave*32 + 16 + l15)*L_;
    const unsigned short* xb  = xT + ((size_t)b*HGROWS + n0) * L_;

    f32x4 acc[2][4];
    #pragma unroll
    for (int i = 0; i < 2; ++i)
        #pragma unroll
        for (int j = 0; j < 4; ++j) acc[i][j] = (f32x4){0.f,0.f,0.f,0.f};

    bf16x8 af[4][2];
#define LDA(s_, ks_) { af[s_][0] = *(const bf16x8*)&apA[(ks_)*32 + kgrp*8];      \
                       af[s_][1] = *(const bf16x8*)&apB[(ks_)*32 + kgrp*8]; }
    LDA(0, 0); LDA(1, 1); LDA(2, 2);
    #pragma unroll
    for (int ks = 0; ks < 16; ++ks) {
        if (ks + 3 < 16) LDA((ks + 3) & 3, ks + 3);
        const int cur = ks & 3;
        #pragma unroll
        for (int fn = 0; fn < 4; ++fn) {
            bf16x8 bfr = *(const bf16x8*)&xb[(size_t)(fn*16 + l15)*L_ + ks*32 + kgrp*8];
            acc[0][fn] = __builtin_amdgcn_mfma_f32_16x16x32_bf16(af[cur][0], bfr, acc[0][fn], 0, 0, 0);
            acc[1][fn] = __builtin_amdgcn_mfma_f32_16x16x32_bf16(af[cur][1], bfr, acc[1][fn], 0, 0, 0);
        }
    }
#undef LDA

    // ---- epilogue: hg[b][n0+nl][er] + K-ext ----
    unsigned short* hgb = hg + ((size_t)b * HGROWS + n0) * KB2;
    const float* mrow = meanv + (size_t)b*HGROWS + n0;
    const float* srow = sdev  + (size_t)b*HGROWS + n0;
    #pragma unroll
    for (int fm = 0; fm < 2; ++fm) {
        int er0 = wave*32 + fm*16 + kgrp*4;
        int e = er0 >> 5;
        f32x4 c4 = *(const f32x4*)&cs1[er0];
        #pragma unroll
        for (int fn = 0; fn < 4; ++fn) {
            int nl = fn*16 + l15;
            int gnn = n0 + nl; if (gnn > N_-1) gnn = N_-1;
            float g = gate[gnn*E_ + e];
            float m = mrow[nl];
            u16x4 pk;
            #pragma unroll
            for (int j = 0; j < 4; ++j)
                pk[j] = f2bf(g * (acc[fm][fn][j] - m * c4[j]));
            *(u16x4*)&hgb[(size_t)nl*KB2 + er0] = pk;
        }
    }
    {   // K-extension cols 256..287, 64 rows x 8 segs (512 threads)
        int nl = tid >> 3, seg = tid & 7;
        int gnn = n0 + nl; if (gnn > N_-1) gnn = N_-1;
        float sd = srow[nl], m = mrow[nl];
        u16x4 pk;
        #pragma unroll
        for (int jj = 0; jj < 4; ++jj) {
            int k = seg*4 + jj;
            float v = (k < E_) ? gate[gnn*E_ + k] * sd : ((k == E_) ? m : 0.f);
            pk[jj] = f2bf(v);
        }
        *(u16x4*)&hgb[(size_t)nl*KB2 + ER_ + seg*4] = pk;
    }
}

// ---------------- GEMM2: out = w2x . hg^T, one LDS stage + barrier ----------
// grid 2304 = 8 xcd * (8 b * (6 pt * 6 nt)); BM=128 p, BN=64 n, K=288.
#define HGS 296   // u16 LDS stride (148 dw -> 2-way aliasing, free)
__global__ __launch_bounds__(512, 6) void gemm2_kernel(
        const unsigned short* __restrict__ hg, const unsigned short* __restrict__ w2x,
        float* __restrict__ out) {
    __shared__ __align__(16) char smem[64 * HGS * 2];      // 37888 B
    unsigned short* hgL = (unsigned short*)smem;           // [64][296]
    const int bid = blockIdx.x;
    const int xcd = bid & 7;
    const int idx = bid >> 3;            // 0..287
    const int b   = (xcd << 3) + idx / 36;
    const int rem = idx % 36;
    const int p0  = (rem / 6) * 128;
    const int n0  = (rem % 6) * 64;

    const int tid  = threadIdx.x;
    const int lane = tid & 63;
    const int wave = tid >> 6;
    const int l15  = lane & 15;
    const int kgrp = lane >> 4;

    // stage hg tile [64][288] -> LDS (16B chunks, 36 per row)
    const unsigned short* hgb = hg + ((size_t)b * HGROWS + n0) * KB2;
    #pragma unroll
    for (int it = 0; it < 5; ++it) {
        int c = tid + it*512;
        if (c < 64*36) {
            int row = c / 36, col = c % 36;
            *(u16x8*)&hgL[(size_t)row*HGS + col*8] =
                *(const u16x8*)&hgb[(size_t)row*KB2 + col*8];
        }
    }
    __syncthreads();

    // K-loop: wave owns 16 p-rows; A-frags from L2-hot w2x, B-frags from LDS
    int prow = p0 + wave*16 + l15; if (prow > P_-1) prow = P_-1;
    const unsigned short* ap = w2x + (size_t)prow*KB2;
    f32x4 o[4];
    #pragma unroll
    for (int j = 0; j < 4; ++j) o[j] = (f32x4){0.f,0.f,0.f,0.f};
    #pragma unroll
    for (int ks = 0; ks < 9; ++ks) {
        bf16x8 afr = *(const bf16x8*)&ap[ks*32 + kgrp*8];
        #pragma unroll
        for (int fn = 0; fn < 4; ++fn) {
            bf16x8 bfr = *(const bf16x8*)&hgL[(size_t)(fn*16 + l15)*HGS + ks*32 + kgrp*8];
            o[fn] = __builtin_amdgcn_mfma_f32_16x16x32_bf16(afr, bfr, o[fn], 0, 0, 0);
        }
    }
    __syncthreads();   // all waves done reading hgL; patch may overwrite

    // patch-transpose: D rows p_loc = kgrp*4+j, cols n_loc = fn*16+l15
    float* patch = (float*)smem + wave * 1088;   // [16][68] f32 = 4352 B
    #pragma unroll
    for (int fn = 0; fn < 4; ++fn)
        #pragma unroll
        for (int j = 0; j < 4; ++j)
            patch[(kgrp*4 + j)*68 + fn*16 + l15] = o[fn][j];
    const int pw0 = p0 + wave*16;
    #pragma unroll
    for (int pass = 0; pass < 4; ++pass) {
        int ploc = pass*4 + kgrp;
        f32x4 v = *(const f32x4*)&patch[ploc*68 + l15*4];
        int p = pw0 + ploc;
        int n = n0 + l15*4;
        if (p < P_) {
            float* orow = out + ((size_t)b*P_ + p)*N_;
            if (n + 3 < N_) {
                *(f32x4*)&orow[n] = v;
            } else {
                #pragma unroll
                for (int j = 0; j < 4; ++j)
                    if (n + j < N_) orow[n + j] = v[j];
            }
        }
    }
}

extern "C" void kernel_launch(void* const* d_in, const int* in_sizes, int n_in,
                              void* d_out, int out_size, void* d_ws, size_t ws_size,
                              hipStream_t stream) {
    const float* x     = (const float*)d_in[0];
    const float* ident = (const float*)d_in[1];
    const float* rw1   = (const float*)d_in[2];
    const float* rb1   = (const float*)d_in[3];
    const float* rw2   = (const float*)d_in[4];
    const float* rb2   = (const float*)d_in[5];
    const float* w1    = (const float*)d_in[6];
    const float* w2    = (const float*)d_in[7];
    const float* bias  = (const float*)d_in[8];
    float* out = (float*)d_out;
    float* ws  = (float*)d_ws;

    float* gate  = ws + OFF_GATE;
    float* cs1   = ws + OFF_CS1;
    float* meanv = ws + OFF_MEAN;
    float* sdev  = ws + OFF_SDEV;
    float* p1    = ws + OFF_P1;
    float* p2    = ws + OFF_P2;
    unsigned short* w1k = (unsigned short*)(ws + OFF_W1K);
    unsigned short* w2x = (unsigned short*)(ws + OFF_W2X);
    unsigned short* xT  = (unsigned short*)(ws + OFF_XT);
    unsigned short* hg  = (unsigned short*)(ws + OFF_HG);

    router_kernel<<<N_, 64, 0, stream>>>(ident, rw1, rb1, rw2, rb2, gate);
    prep_kernel<<<256 + 720 + 8, 512, 0, stream>>>(w1, w2, bias, w1k, w2x, cs1);
    prepx_kernel<<<3072, 256, 0, stream>>>(x, xT, p1, p2);
    statred_kernel<<<(B_*HGROWS)/256, 256, 0, stream>>>(p1, p2, meanv, sdev);
    gemm1_kernel<<<dim3(384), 512, 0, stream>>>(xT, w1k, gate, cs1, meanv, sdev, hg);
    gemm2_kernel<<<dim3(2304), 512, 0, stream>>>(hg, w2x, out);
}